// Round 2
// baseline (370.360 us; speedup 1.0000x reference)
//
#include <hip/hip_runtime.h>

// CIN_51539607712 — R5: 4-way K-split, 16 waves/block, 4 waves/SIMD.
// out[r,n] = sum_h xl[r,h] * Y_h[r,n],  Y_h[r,n] = sum_m x0[r,m] W[h*32+m,n].
// Y via 3 bf16 MFMAs (x0h*wh + x0h*wl + x0l*wh), then fp32 fma by xl (exact).
// Block = 64 rows x 128 cols, 1024 thr = 16 waves: (kh = w&3 K-quarter,
// nq = w>>2 N-quarter). Per-wave private 4 KB W quarter-images, double-
// buffered, XOR-swizzled, staged via global_load_lds w=16; barrier-free
// K-loop with depth-2 counted-vmcnt pipeline (R4). LDS = 128 KB (dynamic).
// R5 change: occupancy was the binding constraint (18% = 2 waves/SIMD,
// MfmaUtil 40%): split K 4-ways instead of 2 so each CU holds 16 waves
// (4/SIMD) — idle phases of one wave overlap MFMA clusters of another.
// Epilogue reduces 4 partials through LDS.

typedef unsigned int u32;
typedef __attribute__((ext_vector_type(8))) short short8;
typedef __attribute__((ext_vector_type(4))) float f32x4;
typedef __attribute__((ext_vector_type(4))) u32 u32x4;

#define R_TOTAL 16384
#define GLOBAL_AS __attribute__((address_space(1)))
#define LDS_AS __attribute__((address_space(3)))

union PackU { u32 u[4]; short8 s; };
union PackB { u32x4 v; short8 s; };

// pack bf16(a) into low half, bf16(b) into high half (truncation)
__device__ __forceinline__ u32 pack_trunc(float a, float b) {
  return __builtin_amdgcn_perm(__float_as_uint(b), __float_as_uint(a), 0x07060302u);
}

// ---------------- prep: X0T[m][b*16+d] = in[b][m][d]  (32 x 16384) ----------
__global__ __launch_bounds__(256) void build_x0t(const float* __restrict__ in,
                                                 float* __restrict__ x0t) {
  __shared__ float t[4096];
  const int tid = threadIdx.x;
  const int b0 = blockIdx.x * 8;
  #pragma unroll
  for (int rep = 0; rep < 4; ++rep) {
    int idx = tid + rep * 256;
    *(float4*)&t[idx * 4] = *(const float4*)&in[(size_t)b0 * 512 + idx * 4];
  }
  __syncthreads();
  #pragma unroll
  for (int rep = 0; rep < 4; ++rep) {
    int idx = tid + rep * 256;     // 0..1023: m(32) x bl(8) x dq(4)
    int m = idx >> 5, rem = idx & 31;
    int bl = rem >> 2, dq = rem & 3;
    *(float4*)&x0t[(size_t)m * R_TOTAL + (b0 + bl) * 16 + dq * 4] =
        *(const float4*)&t[bl * 512 + m * 16 + dq * 4];
  }
}

// ---------------- prep: split+swizzle W into 4 KB quarter images -------------
// Block (t = bid>>2, nq = bid&3). Image: [nl 0..31][p 0..7] 16B blocks; position
// p holds logical block l = p ^ (nl&7); l = h*4+q -> split-part h of
// W[t*32+q*8+j][nq*32+nl], j pairs packed (even=lo half, odd=hi half).
__global__ __launch_bounds__(256) void swizzle_w(const float* __restrict__ W,
                                                 u32* __restrict__ wt) {
  __shared__ float wl[32 * 33];
  const int tid = threadIdx.x;
  const int t = blockIdx.x >> 2, nq = blockIdx.x & 3;
  {
    int kk = tid >> 3, c4 = tid & 7;
    float4 v = *(const float4*)&W[(size_t)(t * 32 + kk) * 128 + nq * 32 + c4 * 4];
    wl[kk * 33 + c4 * 4 + 0] = v.x;
    wl[kk * 33 + c4 * 4 + 1] = v.y;
    wl[kk * 33 + c4 * 4 + 2] = v.z;
    wl[kk * 33 + c4 * 4 + 3] = v.w;
  }
  __syncthreads();
  {
    int nl = tid >> 3, p = tid & 7;
    int l = p ^ (nl & 7);
    int h = l >> 2, q = l & 3;
    u32 o[4];
    #pragma unroll
    for (int jj = 0; jj < 4; ++jj) {
      float v0 = wl[(q * 8 + 2 * jj + 0) * 33 + nl];
      float v1 = wl[(q * 8 + 2 * jj + 1) * 33 + nl];
      if (h == 1) {
        v0 -= __uint_as_float(__float_as_uint(v0) & 0xffff0000u);
        v1 -= __uint_as_float(__float_as_uint(v1) & 0xffff0000u);
      }
      o[jj] = pack_trunc(v0, v1);
    }
    *(u32x4*)(wt + (size_t)(t * 4 + nq) * 1024 + nl * 32 + p * 4) =
        u32x4{o[0], o[1], o[2], o[3]};
  }
}

// ---------------- per-wave tile staging: 4096 B via global_load_lds ----------
__device__ __forceinline__ void stage4k(const u32* g, u32* l, int lane) {
  const GLOBAL_AS u32* gp = (const GLOBAL_AS u32*)g;
  LDS_AS u32* lp = (LDS_AS u32*)l;
  #pragma unroll
  for (int i = 0; i < 4; ++i)
    __builtin_amdgcn_global_load_lds(gp + i * 256 + lane * 4, lp + i * 256, 16, 0, 0);
}

// K-loop iteration. WAITIMM: 0x0F78 = vmcnt(8) (group I done, group I+1 in
// flight), 0x0F70 = vmcnt(0) (peeled last iter). SLOT = I&1 (compile-time).
// Group issue order is always [stage4k(4), xl(4)] -> 8 vmem ops per group.
#define KITER(I, SLOT, WAITIMM, DO_STAGE)                                      \
  {                                                                            \
    __builtin_amdgcn_s_waitcnt(WAITIMM);                                       \
    __builtin_amdgcn_sched_barrier(0);                                         \
    f32x4 xlc[4];                                                              \
    xlc[0] = xn[SLOT][0]; xlc[1] = xn[SLOT][1];                                \
    xlc[2] = xn[SLOT][2]; xlc[3] = xn[SLOT][3];                                \
    const u32* buf = mybuf + (SLOT) * 1024;                                    \
    PackB bh0, bl0, bh1, bl1;                                                  \
    {                                                                          \
      const u32* row0 = buf + ln15 * 32;                                       \
      bh0.v = *(const u32x4*)(row0 + ((q ^ sw) * 4));                          \
      bl0.v = *(const u32x4*)(row0 + (((4 + q) ^ sw) * 4));                    \
      const u32* row1 = buf + (16 + ln15) * 32;                                \
      bh1.v = *(const u32x4*)(row1 + ((q ^ sw) * 4));                          \
      bl1.v = *(const u32x4*)(row1 + (((4 + q) ^ sw) * 4));                    \
    }                                                                          \
    asm volatile("s_waitcnt lgkmcnt(0)" ::: "memory");                         \
    __builtin_amdgcn_sched_barrier(0);                                         \
    if (DO_STAGE) {                                                            \
      stage4k(wt + (size_t)((t0 + (I) + 2) * 4 + nq) * 1024,                   \
              mybuf + (SLOT) * 1024, lane);                                    \
      const float* xp = xt + (size_t)(t0 + (I) + 2) * R_TOTAL + r0;            \
      xn[SLOT][0] = *(const f32x4*)(xp + 0 + q * 4);                           \
      xn[SLOT][1] = *(const f32x4*)(xp + 16 + q * 4);                          \
      xn[SLOT][2] = *(const f32x4*)(xp + 32 + q * 4);                          \
      xn[SLOT][3] = *(const f32x4*)(xp + 48 + q * 4);                          \
    }                                                                          \
    __builtin_amdgcn_sched_barrier(0);                                         \
    __builtin_amdgcn_s_setprio(1);                                             \
    _Pragma("unroll")                                                          \
    for (int f = 0; f < 4; ++f) {                                              \
      f32x4 Y = __builtin_amdgcn_mfma_f32_16x16x32_bf16(Ah[f].s, bh0.s, zero4, 0, 0, 0); \
      Y = __builtin_amdgcn_mfma_f32_16x16x32_bf16(Ah[f].s, bl0.s, Y, 0, 0, 0); \
      Y = __builtin_amdgcn_mfma_f32_16x16x32_bf16(Al[f].s, bh0.s, Y, 0, 0, 0); \
      acc[f][0] += xlc[f] * Y;                                                 \
    }                                                                          \
    _Pragma("unroll")                                                          \
    for (int f = 0; f < 4; ++f) {                                              \
      f32x4 Y = __builtin_amdgcn_mfma_f32_16x16x32_bf16(Ah[f].s, bh1.s, zero4, 0, 0, 0); \
      Y = __builtin_amdgcn_mfma_f32_16x16x32_bf16(Ah[f].s, bl1.s, Y, 0, 0, 0); \
      Y = __builtin_amdgcn_mfma_f32_16x16x32_bf16(Al[f].s, bh1.s, Y, 0, 0, 0); \
      acc[f][1] += xlc[f] * Y;                                                 \
    }                                                                          \
    __builtin_amdgcn_s_setprio(0);                                             \
    __builtin_amdgcn_sched_barrier(0);                                         \
  }

// ---------------- main layer kernel ----------------
// 16 waves: kh = w&3 (K quarter), nq = w>>2 (N quarter). LDS 128 KB dynamic:
// 16 regions x 2048 u32 (per-wave 4 KB dbuf x2; reused as partial-acc dump).
template <int NT, bool RELU, bool STORE_X>
__global__ __launch_bounds__(1024, 4) void layer_mfma(
    const float* __restrict__ xt,    // NT x R (transposed prev activation)
    const float* __restrict__ x0t,   // 32 x R
    const u32* __restrict__ wt,      // NT*4 quarter images (1024 u32 each)
    const float* __restrict__ bias,  // 128
    float* __restrict__ xoutT,       // 128 x R (if STORE_X)
    float* __restrict__ osum)        // d_out + layer offset, stride 384
{
  constexpr int HT = NT / 4;
  static_assert((HT & 1) == 0 && HT >= 4, "pair-loop needs even HT >= 4");
  extern __shared__ u32 smem[];      // 128 KB: 16 waves x 2048 u32

  const int tid = threadIdx.x;
  const int w = tid >> 6, lane = tid & 63;
  const int ln15 = lane & 15, q = lane >> 4;
  const int kh = w & 3, nq = w >> 2;
  const int r0 = blockIdx.x * 64;
  const int sw = ln15 & 7;
  u32* mybuf = smem + w * 2048;

  // ---- loop-invariant A fragments: split x0 rows (A[i=ln15][k=q*8+j]) ----
  PackU Ah[4], Al[4];
  #pragma unroll
  for (int f = 0; f < 4; ++f) {
    const int rbase = r0 + f * 16 + ln15;
    float e[8];
    #pragma unroll
    for (int j = 0; j < 8; ++j) e[j] = x0t[(size_t)(q * 8 + j) * R_TOTAL + rbase];
    #pragma unroll
    for (int jj = 0; jj < 4; ++jj) {
      float z0 = e[2 * jj], z1 = e[2 * jj + 1];
      Ah[f].u[jj] = pack_trunc(z0, z1);
      float h0 = __uint_as_float(__float_as_uint(z0) & 0xffff0000u);
      float h1 = __uint_as_float(__float_as_uint(z1) & 0xffff0000u);
      Al[f].u[jj] = pack_trunc(z0 - h0, z1 - h1);
    }
  }

  f32x4 acc[4][2];
  #pragma unroll
  for (int f = 0; f < 4; ++f)
    #pragma unroll
    for (int c = 0; c < 2; ++c) acc[f][c] = f32x4{0.f, 0.f, 0.f, 0.f};
  const f32x4 zero4 = {0.f, 0.f, 0.f, 0.f};

  const int t0 = kh * HT;

  // ---- prologue: 2-deep prefetch (groups 0 and 1), issue order stage,xl ----
  f32x4 xn[2][4];
  stage4k(wt + (size_t)(t0 * 4 + nq) * 1024, mybuf, lane);
  {
    const float* xp = xt + (size_t)t0 * R_TOTAL + r0;
    xn[0][0] = *(const f32x4*)(xp + 0 + q * 4);
    xn[0][1] = *(const f32x4*)(xp + 16 + q * 4);
    xn[0][2] = *(const f32x4*)(xp + 32 + q * 4);
    xn[0][3] = *(const f32x4*)(xp + 48 + q * 4);
  }
  stage4k(wt + (size_t)((t0 + 1) * 4 + nq) * 1024, mybuf + 1024, lane);
  {
    const float* xp = xt + (size_t)(t0 + 1) * R_TOTAL + r0;
    xn[1][0] = *(const f32x4*)(xp + 0 + q * 4);
    xn[1][1] = *(const f32x4*)(xp + 16 + q * 4);
    xn[1][2] = *(const f32x4*)(xp + 32 + q * 4);
    xn[1][3] = *(const f32x4*)(xp + 48 + q * 4);
  }
  __builtin_amdgcn_sched_barrier(0);

  // ---- steady state: every in-loop iter stages (i+2), waits vmcnt(8) ----
  for (int i = 0; i < HT - 2; i += 2) {
    KITER(i, 0, 0x0F78, 1);
    KITER(i + 1, 1, 0x0F78, 1);
  }
  // ---- peeled last pair: no staging; final iter drains to vmcnt(0) ----
  KITER(HT - 2, 0, 0x0F78, 0);
  KITER(HT - 1, 1, 0x0F70, 0);

  // ---------------- epilogue: 4-way partial reduction ----------------
  __syncthreads();                  // K-loop LDS regions now reusable
  if (kh != 0) {                    // dump partial acc into own region (8 KB)
    u32* reg = mybuf;
    #pragma unroll
    for (int f = 0; f < 4; ++f)
      #pragma unroll
      for (int c = 0; c < 2; ++c)
        *(f32x4*)(reg + ((size_t)(f * 2 + c) * 64 + lane) * 4) = acc[f][c];
  }
  __syncthreads();
  if (kh == 0) {
    float bs[2];
    #pragma unroll
    for (int c = 0; c < 2; ++c) bs[c] = bias[nq * 32 + c * 16 + ln15];

    f32x4 vv[4][2];
    #pragma unroll
    for (int f = 0; f < 4; ++f) {
      #pragma unroll
      for (int c = 0; c < 2; ++c) {
        f32x4 v = acc[f][c];
        #pragma unroll
        for (int p = 1; p < 4; ++p) {     // partners w+1..w+3 (kh=1..3, same nq)
          const u32* reg = smem + (size_t)(w + p) * 2048;
          v += *(const f32x4*)(reg + ((size_t)(f * 2 + c) * 64 + lane) * 4);
        }
        v.x += bs[c]; v.y += bs[c]; v.z += bs[c]; v.w += bs[c];
        if (RELU) {
          v.x = fmaxf(v.x, 0.f); v.y = fmaxf(v.y, 0.f);
          v.z = fmaxf(v.z, 0.f); v.w = fmaxf(v.w, 0.f);
        }
        vv[f][c] = v;
        float s = v.x + v.y + v.z + v.w;       // 4 rows of batch (r0>>4)+f
        s += __shfl_xor(s, 16, 64);
        s += __shfl_xor(s, 32, 64);
        if (q == 0)
          osum[(size_t)((r0 >> 4) + f) * 384 + nq * 32 + c * 16 + ln15] = s;
      }
    }

    if (STORE_X) {
      // transpose via own LDS region, then 64B-contiguous stores to XT.
      u32* myreg = mybuf;
      #pragma unroll
      for (int f = 0; f < 4; ++f)
        #pragma unroll
        for (int c = 0; c < 2; ++c)
          *(f32x4*)(myreg + ((size_t)(f * 2 + c) * 64 + lane) * 4) = vv[f][c];
      // element (r_local, lcol): frag (f=r>>4, c=lcol>>4), lane q=(r>>2)&3,
      // ln15=lcol&15, comp rr=r&3. Round (c,s): lane -> col=c*16+(lane>>2),
      // r_local = s*16 + (lane&3)*4.
      #pragma unroll
      for (int c = 0; c < 2; ++c) {
        #pragma unroll
        for (int s = 0; s < 4; ++s) {
          f32x4 vr = *(const f32x4*)(myreg +
              ((size_t)(s * 2 + c) * 64 + (lane & 3) * 16 + (lane >> 2)) * 4);
          const int col = nq * 32 + c * 16 + (lane >> 2);
          *(f32x4*)&xoutT[(size_t)col * R_TOTAL + r0 + s * 16 + (lane & 3) * 4] = vr;
        }
      }
    }
  }
}

extern "C" void kernel_launch(void* const* d_in, const int* in_sizes, int n_in,
                              void* d_out, int out_size, void* d_ws, size_t ws_size,
                              hipStream_t stream) {
  const float* in = (const float*)d_in[0];
  const float* W0 = (const float*)d_in[1];
  const float* b0 = (const float*)d_in[2];
  const float* W1 = (const float*)d_in[3];
  const float* b1 = (const float*)d_in[4];
  const float* W2 = (const float*)d_in[5];
  const float* b2 = (const float*)d_in[6];
  float* out = (float*)d_out;

  float* X0T = (float*)d_ws;                         // 32 x 16384   (2 MB)
  float* X1T = X0T + (size_t)32 * R_TOTAL;           // 128 x 16384  (8 MB)
  float* X2T = X1T + (size_t)128 * R_TOTAL;          // 128 x 16384  (8 MB)
  u32* Wt0 = (u32*)(X2T + (size_t)128 * R_TOTAL);    // 32*4*1024 u32  (0.5 MB)
  u32* Wt1 = Wt0 + (size_t)32 * 4 * 1024;            // 128*4*1024 u32 (2 MB)
  u32* Wt2 = Wt1 + (size_t)128 * 4 * 1024;           // 128*4*1024 u32 (2 MB)
  // total ws: 22.5 MB

  build_x0t<<<128, 256, 0, stream>>>(in, X0T);
  swizzle_w<<<128, 256, 0, stream>>>(W0, Wt0);
  swizzle_w<<<512, 256, 0, stream>>>(W1, Wt1);
  swizzle_w<<<512, 256, 0, stream>>>(W2, Wt2);

  constexpr size_t kLds = 16 * 2048 * sizeof(u32);   // 128 KB dynamic LDS

  layer_mfma<32, true, true><<<256, 1024, kLds, stream>>>(X0T, X0T, Wt0, b0, X1T, out + 0);
  layer_mfma<128, true, true><<<256, 1024, kLds, stream>>>(X1T, X0T, Wt1, b1, X2T, out + 128);
  layer_mfma<128, false, false><<<256, 1024, kLds, stream>>>(X2T, X0T, Wt2, b2, nullptr, out + 256);
}

// Round 4
// 212.053 us; speedup vs baseline: 1.7465x; 1.7465x over previous
//
#include <hip/hip_runtime.h>

// CIN_51539607712 — R6b: resubmit of R6 (container infra failure, no data).
// 32-row blocks, 2 blocks/CU, 4 waves/SIMD (no spill).
// out[r,n] = sum_h xl[r,h] * Y_h[r,n],  Y_h[r,n] = sum_m x0[r,m] W[h*32+m,n].
// Y via 3 bf16 MFMAs (x0h*wh + x0h*wl + x0l*wh), then fp32 fma by xl (exact).
// Block = 32 rows x 128 cols, 512 thr = 8 waves: (kh = w&1 K-half,
// nq = w>>1 N-quarter). Per-wave private 4 KB W quarter-images, double-
// buffered, XOR-swizzled, staged via global_load_lds w=16; barrier-free
// K-loop, depth-2 counted-vmcnt pipeline (group = 4 stage + 2 xl = 6 vmem).
// R6 lesson (from R5): 16-wave blocks forced VGPR=64 -> 230 MB spill traffic.
// This config doubles waves/SIMD via MORE BLOCKS (grid 512, 64 KB LDS ->
// 2 blocks/CU) while halving per-wave state (f=0..1), keeping VGPR ~75.

typedef unsigned int u32;
typedef __attribute__((ext_vector_type(8))) short short8;
typedef __attribute__((ext_vector_type(4))) float f32x4;
typedef __attribute__((ext_vector_type(4))) u32 u32x4;

#define R_TOTAL 16384
#define GLOBAL_AS __attribute__((address_space(1)))
#define LDS_AS __attribute__((address_space(3)))

union PackU { u32 u[4]; short8 s; };
union PackB { u32x4 v; short8 s; };

// pack bf16(a) into low half, bf16(b) into high half (truncation)
__device__ __forceinline__ u32 pack_trunc(float a, float b) {
  return __builtin_amdgcn_perm(__float_as_uint(b), __float_as_uint(a), 0x07060302u);
}

// ---------------- prep: X0T[m][b*16+d] = in[b][m][d]  (32 x 16384) ----------
__global__ __launch_bounds__(256) void build_x0t(const float* __restrict__ in,
                                                 float* __restrict__ x0t) {
  __shared__ float t[4096];
  const int tid = threadIdx.x;
  const int b0 = blockIdx.x * 8;
  #pragma unroll
  for (int rep = 0; rep < 4; ++rep) {
    int idx = tid + rep * 256;
    *(float4*)&t[idx * 4] = *(const float4*)&in[(size_t)b0 * 512 + idx * 4];
  }
  __syncthreads();
  #pragma unroll
  for (int rep = 0; rep < 4; ++rep) {
    int idx = tid + rep * 256;     // 0..1023: m(32) x bl(8) x dq(4)
    int m = idx >> 5, rem = idx & 31;
    int bl = rem >> 2, dq = rem & 3;
    *(float4*)&x0t[(size_t)m * R_TOTAL + (b0 + bl) * 16 + dq * 4] =
        *(const float4*)&t[bl * 512 + m * 16 + dq * 4];
  }
}

// ---------------- prep: split+swizzle W into 4 KB quarter images -------------
// Block (t = bid>>2, nq = bid&3). Image: [nl 0..31][p 0..7] 16B blocks; position
// p holds logical block l = p ^ (nl&7); l = h*4+q -> split-part h of
// W[t*32+q*8+j][nq*32+nl], j pairs packed (even=lo half, odd=hi half).
__global__ __launch_bounds__(256) void swizzle_w(const float* __restrict__ W,
                                                 u32* __restrict__ wt) {
  __shared__ float wl[32 * 33];
  const int tid = threadIdx.x;
  const int t = blockIdx.x >> 2, nq = blockIdx.x & 3;
  {
    int kk = tid >> 3, c4 = tid & 7;
    float4 v = *(const float4*)&W[(size_t)(t * 32 + kk) * 128 + nq * 32 + c4 * 4];
    wl[kk * 33 + c4 * 4 + 0] = v.x;
    wl[kk * 33 + c4 * 4 + 1] = v.y;
    wl[kk * 33 + c4 * 4 + 2] = v.z;
    wl[kk * 33 + c4 * 4 + 3] = v.w;
  }
  __syncthreads();
  {
    int nl = tid >> 3, p = tid & 7;
    int l = p ^ (nl & 7);
    int h = l >> 2, q = l & 3;
    u32 o[4];
    #pragma unroll
    for (int jj = 0; jj < 4; ++jj) {
      float v0 = wl[(q * 8 + 2 * jj + 0) * 33 + nl];
      float v1 = wl[(q * 8 + 2 * jj + 1) * 33 + nl];
      if (h == 1) {
        v0 -= __uint_as_float(__float_as_uint(v0) & 0xffff0000u);
        v1 -= __uint_as_float(__float_as_uint(v1) & 0xffff0000u);
      }
      o[jj] = pack_trunc(v0, v1);
    }
    *(u32x4*)(wt + (size_t)(t * 4 + nq) * 1024 + nl * 32 + p * 4) =
        u32x4{o[0], o[1], o[2], o[3]};
  }
}

// ---------------- per-wave tile staging: 4096 B via global_load_lds ----------
__device__ __forceinline__ void stage4k(const u32* g, u32* l, int lane) {
  const GLOBAL_AS u32* gp = (const GLOBAL_AS u32*)g;
  LDS_AS u32* lp = (LDS_AS u32*)l;
  #pragma unroll
  for (int i = 0; i < 4; ++i)
    __builtin_amdgcn_global_load_lds(gp + i * 256 + lane * 4, lp + i * 256, 16, 0, 0);
}

// K-loop iteration. WAITIMM: 0x0F76 = vmcnt(6) (group I done, group I+1's 6
// vmem ops in flight), 0x0F70 = vmcnt(0) (peeled last iter). SLOT = I&1.
// Group issue order is always [stage4k(4), xl(2)] -> 6 vmem ops per group.
#define KITER(I, SLOT, WAITIMM, DO_STAGE)                                      \
  {                                                                            \
    __builtin_amdgcn_s_waitcnt(WAITIMM);                                       \
    __builtin_amdgcn_sched_barrier(0);                                         \
    f32x4 xlc[2];                                                              \
    xlc[0] = xn[SLOT][0]; xlc[1] = xn[SLOT][1];                                \
    const u32* buf = mybuf + (SLOT) * 1024;                                    \
    PackB bh0, bl0, bh1, bl1;                                                  \
    {                                                                          \
      const u32* row0 = buf + ln15 * 32;                                       \
      bh0.v = *(const u32x4*)(row0 + ((q ^ sw) * 4));                          \
      bl0.v = *(const u32x4*)(row0 + (((4 + q) ^ sw) * 4));                    \
      const u32* row1 = buf + (16 + ln15) * 32;                                \
      bh1.v = *(const u32x4*)(row1 + ((q ^ sw) * 4));                          \
      bl1.v = *(const u32x4*)(row1 + (((4 + q) ^ sw) * 4));                    \
    }                                                                          \
    asm volatile("s_waitcnt lgkmcnt(0)" ::: "memory");                         \
    __builtin_amdgcn_sched_barrier(0);                                         \
    if (DO_STAGE) {                                                            \
      stage4k(wt + (size_t)((t0 + (I) + 2) * 4 + nq) * 1024,                   \
              mybuf + (SLOT) * 1024, lane);                                    \
      const float* xp = xt + (size_t)(t0 + (I) + 2) * R_TOTAL + r0;            \
      xn[SLOT][0] = *(const f32x4*)(xp + 0 + q * 4);                           \
      xn[SLOT][1] = *(const f32x4*)(xp + 16 + q * 4);                          \
    }                                                                          \
    __builtin_amdgcn_sched_barrier(0);                                         \
    __builtin_amdgcn_s_setprio(1);                                             \
    _Pragma("unroll")                                                          \
    for (int f = 0; f < 2; ++f) {                                              \
      f32x4 Y = __builtin_amdgcn_mfma_f32_16x16x32_bf16(Ah[f].s, bh0.s, zero4, 0, 0, 0); \
      Y = __builtin_amdgcn_mfma_f32_16x16x32_bf16(Ah[f].s, bl0.s, Y, 0, 0, 0); \
      Y = __builtin_amdgcn_mfma_f32_16x16x32_bf16(Al[f].s, bh0.s, Y, 0, 0, 0); \
      acc[f][0] += xlc[f] * Y;                                                 \
    }                                                                          \
    _Pragma("unroll")                                                          \
    for (int f = 0; f < 2; ++f) {                                              \
      f32x4 Y = __builtin_amdgcn_mfma_f32_16x16x32_bf16(Ah[f].s, bh1.s, zero4, 0, 0, 0); \
      Y = __builtin_amdgcn_mfma_f32_16x16x32_bf16(Ah[f].s, bl1.s, Y, 0, 0, 0); \
      Y = __builtin_amdgcn_mfma_f32_16x16x32_bf16(Al[f].s, bh1.s, Y, 0, 0, 0); \
      acc[f][1] += xlc[f] * Y;                                                 \
    }                                                                          \
    __builtin_amdgcn_s_setprio(0);                                             \
    __builtin_amdgcn_sched_barrier(0);                                         \
  }

// ---------------- main layer kernel ----------------
// 8 waves: kh = w&1 (K half), nq = w>>1 (N quarter). 32-row tiles, grid 512,
// 64 KB static LDS -> 2 blocks/CU = 4 waves/SIMD.
template <int NT, bool RELU, bool STORE_X>
__global__ __launch_bounds__(512, 4) void layer_mfma(
    const float* __restrict__ xt,    // NT x R (transposed prev activation)
    const float* __restrict__ x0t,   // 32 x R
    const u32* __restrict__ wt,      // NT*4 quarter images (1024 u32 each)
    const float* __restrict__ bias,  // 128
    float* __restrict__ xoutT,       // 128 x R (if STORE_X)
    float* __restrict__ osum)        // d_out + layer offset, stride 384
{
  constexpr int HT = NT / 2;
  static_assert((HT & 1) == 0 && HT >= 4, "pair-loop needs even HT >= 4");
  __shared__ u32 smem[16384];        // 64 KB: 8 waves x 2048 u32 (4 KB dbuf x2)

  const int tid = threadIdx.x;
  const int w = tid >> 6, lane = tid & 63;
  const int ln15 = lane & 15, q = lane >> 4;
  const int kh = w & 1, nq = w >> 1;
  const int r0 = blockIdx.x * 32;
  const int sw = ln15 & 7;
  u32* mybuf = smem + w * 2048;

  // ---- loop-invariant A fragments: split x0 rows (A[i=ln15][k=q*8+j]) ----
  PackU Ah[2], Al[2];
  #pragma unroll
  for (int f = 0; f < 2; ++f) {
    const int rbase = r0 + f * 16 + ln15;
    float e[8];
    #pragma unroll
    for (int j = 0; j < 8; ++j) e[j] = x0t[(size_t)(q * 8 + j) * R_TOTAL + rbase];
    #pragma unroll
    for (int jj = 0; jj < 4; ++jj) {
      float z0 = e[2 * jj], z1 = e[2 * jj + 1];
      Ah[f].u[jj] = pack_trunc(z0, z1);
      float h0 = __uint_as_float(__float_as_uint(z0) & 0xffff0000u);
      float h1 = __uint_as_float(__float_as_uint(z1) & 0xffff0000u);
      Al[f].u[jj] = pack_trunc(z0 - h0, z1 - h1);
    }
  }

  f32x4 acc[2][2];
  #pragma unroll
  for (int f = 0; f < 2; ++f)
    #pragma unroll
    for (int c = 0; c < 2; ++c) acc[f][c] = f32x4{0.f, 0.f, 0.f, 0.f};
  const f32x4 zero4 = {0.f, 0.f, 0.f, 0.f};

  const int t0 = kh * HT;

  // ---- prologue: 2-deep prefetch (groups 0 and 1), issue order stage,xl ----
  f32x4 xn[2][2];
  stage4k(wt + (size_t)(t0 * 4 + nq) * 1024, mybuf, lane);
  {
    const float* xp = xt + (size_t)t0 * R_TOTAL + r0;
    xn[0][0] = *(const f32x4*)(xp + 0 + q * 4);
    xn[0][1] = *(const f32x4*)(xp + 16 + q * 4);
  }
  stage4k(wt + (size_t)((t0 + 1) * 4 + nq) * 1024, mybuf + 1024, lane);
  {
    const float* xp = xt + (size_t)(t0 + 1) * R_TOTAL + r0;
    xn[1][0] = *(const f32x4*)(xp + 0 + q * 4);
    xn[1][1] = *(const f32x4*)(xp + 16 + q * 4);
  }
  __builtin_amdgcn_sched_barrier(0);

  // ---- steady state: every in-loop iter stages (i+2), waits vmcnt(6) ----
  for (int i = 0; i < HT - 2; i += 2) {
    KITER(i, 0, 0x0F76, 1);
    KITER(i + 1, 1, 0x0F76, 1);
  }
  // ---- peeled last pair: no staging; final iter drains to vmcnt(0) ----
  KITER(HT - 2, 0, 0x0F76, 0);
  KITER(HT - 1, 1, 0x0F70, 0);

  // ---------------- epilogue ----------------
  __syncthreads();                  // K-loop LDS regions now reusable
  if (kh == 1) {                    // dump partial acc into own region (4 KB)
    u32* reg = mybuf;
    #pragma unroll
    for (int f = 0; f < 2; ++f)
      #pragma unroll
      for (int c = 0; c < 2; ++c)
        *(f32x4*)(reg + ((size_t)(f * 2 + c) * 64 + lane) * 4) = acc[f][c];
  }
  __syncthreads();
  if (kh == 0) {
    const u32* reg = smem + (w + 1) * 2048;   // partner (kh=1, same nq)
    float bs[2];
    #pragma unroll
    for (int c = 0; c < 2; ++c) bs[c] = bias[nq * 32 + c * 16 + ln15];

    f32x4 vv[2][2];
    #pragma unroll
    for (int f = 0; f < 2; ++f) {
      #pragma unroll
      for (int c = 0; c < 2; ++c) {
        f32x4 part = *(const f32x4*)(reg + ((size_t)(f * 2 + c) * 64 + lane) * 4);
        f32x4 v = acc[f][c] + part;
        v.x += bs[c]; v.y += bs[c]; v.z += bs[c]; v.w += bs[c];
        if (RELU) {
          v.x = fmaxf(v.x, 0.f); v.y = fmaxf(v.y, 0.f);
          v.z = fmaxf(v.z, 0.f); v.w = fmaxf(v.w, 0.f);
        }
        vv[f][c] = v;
        float s = v.x + v.y + v.z + v.w;       // 4 rows of batch (r0>>4)+f
        s += __shfl_xor(s, 16, 64);
        s += __shfl_xor(s, 32, 64);
        if (q == 0)
          osum[(size_t)((r0 >> 4) + f) * 384 + nq * 32 + c * 16 + ln15] = s;
      }
    }

    if (STORE_X) {
      // transpose via own LDS region, then 64B-contiguous stores to XT.
      u32* myreg = mybuf;
      #pragma unroll
      for (int f = 0; f < 2; ++f)
        #pragma unroll
        for (int c = 0; c < 2; ++c)
          *(f32x4*)(myreg + ((size_t)(f * 2 + c) * 64 + lane) * 4) = vv[f][c];
      // element (r_local, lcol): frag (f=r>>4, c=lcol>>4), lane q=(r>>2)&3,
      // ln15=lcol&15, comp rr=r&3. Round (c,s): lane -> col=c*16+(lane>>2),
      // r_local = s*16 + (lane&3)*4, s = 0..1 (32 rows).
      #pragma unroll
      for (int c = 0; c < 2; ++c) {
        #pragma unroll
        for (int s = 0; s < 2; ++s) {
          f32x4 vr = *(const f32x4*)(myreg +
              ((size_t)(s * 2 + c) * 64 + (lane & 3) * 16 + (lane >> 2)) * 4);
          const int col = nq * 32 + c * 16 + (lane >> 2);
          *(f32x4*)&xoutT[(size_t)col * R_TOTAL + r0 + s * 16 + (lane & 3) * 4] = vr;
        }
      }
    }
  }
}

extern "C" void kernel_launch(void* const* d_in, const int* in_sizes, int n_in,
                              void* d_out, int out_size, void* d_ws, size_t ws_size,
                              hipStream_t stream) {
  const float* in = (const float*)d_in[0];
  const float* W0 = (const float*)d_in[1];
  const float* b0 = (const float*)d_in[2];
  const float* W1 = (const float*)d_in[3];
  const float* b1 = (const float*)d_in[4];
  const float* W2 = (const float*)d_in[5];
  const float* b2 = (const float*)d_in[6];
  float* out = (float*)d_out;

  float* X0T = (float*)d_ws;                         // 32 x 16384   (2 MB)
  float* X1T = X0T + (size_t)32 * R_TOTAL;           // 128 x 16384  (8 MB)
  float* X2T = X1T + (size_t)128 * R_TOTAL;          // 128 x 16384  (8 MB)
  u32* Wt0 = (u32*)(X2T + (size_t)128 * R_TOTAL);    // 32*4*1024 u32  (0.5 MB)
  u32* Wt1 = Wt0 + (size_t)32 * 4 * 1024;            // 128*4*1024 u32 (2 MB)
  u32* Wt2 = Wt1 + (size_t)128 * 4 * 1024;           // 128*4*1024 u32 (2 MB)
  // total ws: 22.5 MB

  build_x0t<<<128, 256, 0, stream>>>(in, X0T);
  swizzle_w<<<128, 256, 0, stream>>>(W0, Wt0);
  swizzle_w<<<512, 256, 0, stream>>>(W1, Wt1);
  swizzle_w<<<512, 256, 0, stream>>>(W2, Wt2);

  layer_mfma<32, true, true><<<512, 512, 0, stream>>>(X0T, X0T, Wt0, b0, X1T, out + 0);
  layer_mfma<128, true, true><<<512, 512, 0, stream>>>(X1T, X0T, Wt1, b1, X2T, out + 128);
  layer_mfma<128, false, false><<<512, 512, 0, stream>>>(X2T, X0T, Wt2, b2, nullptr, out + 256);
}

// Round 5
// 188.426 us; speedup vs baseline: 1.9655x; 1.1254x over previous
//
#include <hip/hip_runtime.h>

// CIN_51539607712 — R7: R4 config (64-row blocks, grid 256 — best measured)
// + register-level B-fragment double-buffer with counted lgkmcnt(4), and
// vmcnt(4) top-of-iter wait (stage-DMAs of slot i+1 visible during iter i).
// Removes the ~150-cy exposed LDS latency per K-iteration that limited R4
// to MfmaUtil 40%. Prep launches fused 4 -> 1.
// out[r,n] = sum_h xl[r,h] * Y_h[r,n],  Y_h[r,n] = sum_m x0[r,m] W[h*32+m,n].
// Y via 3 bf16 MFMAs (x0h*wh + x0h*wl + x0l*wh), then fp32 fma by xl (exact).
// Block = 64 rows x 128 cols, 512 thr = 8 waves: (kh = w&1 K-half, nq = w>>1
// N-quarter). Per-wave private 4 KB W quarter-images, double-buffered, XOR-
// swizzled, staged via global_load_lds w=16; barrier-free K-loop.
// vmem ledger (8-op groups: stage x4 | SB | xl x4, issued during iter i-2):
//   top of iter i: wait vmcnt(4) -> leaves G(i+1) xl4; drains G(i) xl
//   (this iter's xl) and G(i+1) stage4 (slot i+1 readable).
//   ds_read slot(i+1) into BNXT; wait lgkmcnt(4) -> drains last iter's reads
//   (this iter's fragments, in BCUR); stage G(i+2); MFMA from BCUR.
// R5 lesson: 16-wave blocks -> VGPR 64 cap -> 230 MB spill. R6 lesson: 32-row
// blocks double occupancy but halve MFMA/overhead ratio -> net loss.

typedef unsigned int u32;
typedef __attribute__((ext_vector_type(8))) short short8;
typedef __attribute__((ext_vector_type(4))) float f32x4;
typedef __attribute__((ext_vector_type(4))) u32 u32x4;

#define R_TOTAL 16384
#define GLOBAL_AS __attribute__((address_space(1)))
#define LDS_AS __attribute__((address_space(3)))

union PackU { u32 u[4]; short8 s; };
union PackB { u32x4 v; short8 s; };

// pack bf16(a) into low half, bf16(b) into high half (truncation)
__device__ __forceinline__ u32 pack_trunc(float a, float b) {
  return __builtin_amdgcn_perm(__float_as_uint(b), __float_as_uint(a), 0x07060302u);
}

// ---------------- fused prep kernel ----------------
// blocks 0..127: build X0T[m][b*16+d] = in[b][m][d]  (32 x 16384)
// blocks 128..255 / 256..767 / 768..1279: swizzle W0 / W1 / W2.
__device__ __forceinline__ void build_x0t_body(const float* __restrict__ in,
                                               float* __restrict__ x0t,
                                               int bid, int tid, float* t) {
  const int b0 = bid * 8;
  #pragma unroll
  for (int rep = 0; rep < 4; ++rep) {
    int idx = tid + rep * 256;
    *(float4*)&t[idx * 4] = *(const float4*)&in[(size_t)b0 * 512 + idx * 4];
  }
  __syncthreads();
  #pragma unroll
  for (int rep = 0; rep < 4; ++rep) {
    int idx = tid + rep * 256;     // 0..1023: m(32) x bl(8) x dq(4)
    int m = idx >> 5, rem = idx & 31;
    int bl = rem >> 2, dq = rem & 3;
    *(float4*)&x0t[(size_t)m * R_TOTAL + (b0 + bl) * 16 + dq * 4] =
        *(const float4*)&t[bl * 512 + m * 16 + dq * 4];
  }
}

// Block (t = bid>>2, nq = bid&3). Image: [nl 0..31][p 0..7] 16B blocks; position
// p holds logical block l = p ^ (nl&7); l = h*4+q -> split-part h of
// W[t*32+q*8+j][nq*32+nl], j pairs packed (even=lo half, odd=hi half).
__device__ __forceinline__ void swizzle_body(const float* __restrict__ W,
                                             u32* __restrict__ wt,
                                             int bid, int tid, float* wl) {
  const int t = bid >> 2, nq = bid & 3;
  {
    int kk = tid >> 3, c4 = tid & 7;
    float4 v = *(const float4*)&W[(size_t)(t * 32 + kk) * 128 + nq * 32 + c4 * 4];
    wl[kk * 33 + c4 * 4 + 0] = v.x;
    wl[kk * 33 + c4 * 4 + 1] = v.y;
    wl[kk * 33 + c4 * 4 + 2] = v.z;
    wl[kk * 33 + c4 * 4 + 3] = v.w;
  }
  __syncthreads();
  {
    int nl = tid >> 3, p = tid & 7;
    int l = p ^ (nl & 7);
    int h = l >> 2, q = l & 3;
    u32 o[4];
    #pragma unroll
    for (int jj = 0; jj < 4; ++jj) {
      float v0 = wl[(q * 8 + 2 * jj + 0) * 33 + nl];
      float v1 = wl[(q * 8 + 2 * jj + 1) * 33 + nl];
      if (h == 1) {
        v0 -= __uint_as_float(__float_as_uint(v0) & 0xffff0000u);
        v1 -= __uint_as_float(__float_as_uint(v1) & 0xffff0000u);
      }
      o[jj] = pack_trunc(v0, v1);
    }
    *(u32x4*)(wt + (size_t)(t * 4 + nq) * 1024 + nl * 32 + p * 4) =
        u32x4{o[0], o[1], o[2], o[3]};
  }
}

__global__ __launch_bounds__(256) void prep_all(
    const float* __restrict__ in, float* __restrict__ x0t,
    const float* __restrict__ W0, u32* __restrict__ wt0,
    const float* __restrict__ W1, u32* __restrict__ wt1,
    const float* __restrict__ W2, u32* __restrict__ wt2) {
  __shared__ float sh[4096];
  const int b = blockIdx.x, tid = threadIdx.x;
  if (b < 128)      build_x0t_body(in, x0t, b, tid, sh);
  else if (b < 256) swizzle_body(W0, wt0, b - 128, tid, sh);
  else if (b < 768) swizzle_body(W1, wt1, b - 256, tid, sh);
  else              swizzle_body(W2, wt2, b - 768, tid, sh);
}

// ---------------- per-wave tile staging: 4096 B via global_load_lds ----------
__device__ __forceinline__ void stage4k(const u32* g, u32* l, int lane) {
  const GLOBAL_AS u32* gp = (const GLOBAL_AS u32*)g;
  LDS_AS u32* lp = (LDS_AS u32*)l;
  #pragma unroll
  for (int i = 0; i < 4; ++i)
    __builtin_amdgcn_global_load_lds(gp + i * 256 + lane * 4, lp + i * 256, 16, 0, 0);
}

// s_waitcnt imm encodings (gfx9): vm[3:0]=b3:0, exp=b6:4, lgkm=b11:8, vm[5:4]=b15:14
// 0x0F74 = vmcnt(4)  0x0F70 = vmcnt(0)  0xC47F = lgkmcnt(4)  0xC07F = lgkmcnt(0)
#define SB() __builtin_amdgcn_sched_barrier(0)

// KITER: one K-step. BCUR = fragments for this iter (read last iter);
// BNXT = fragments for next iter (read now, waited next iter via lgkmcnt(4)).
#define KITER(I, SLOT, TOPW, LGKM, DO_STAGE, READ_NEXT, BCUR, BNXT)            \
  {                                                                            \
    __builtin_amdgcn_s_waitcnt(TOPW);                                          \
    SB();                                                                      \
    if (READ_NEXT) {                                                           \
      const u32* nbuf = mybuf + ((SLOT) ^ 1) * 1024;                           \
      const u32* nrow0 = nbuf + ln15 * 32;                                     \
      BNXT[0].v = *(const u32x4*)(nrow0 + ((q ^ sw) * 4));                     \
      BNXT[1].v = *(const u32x4*)(nrow0 + (((4 + q) ^ sw) * 4));               \
      const u32* nrow1 = nbuf + (16 + ln15) * 32;                              \
      BNXT[2].v = *(const u32x4*)(nrow1 + ((q ^ sw) * 4));                     \
      BNXT[3].v = *(const u32x4*)(nrow1 + (((4 + q) ^ sw) * 4));               \
    }                                                                          \
    SB();                                                                      \
    f32x4 xlc[4];                                                              \
    xlc[0] = xn[SLOT][0]; xlc[1] = xn[SLOT][1];                                \
    xlc[2] = xn[SLOT][2]; xlc[3] = xn[SLOT][3];                                \
    __builtin_amdgcn_s_waitcnt(LGKM);                                          \
    SB();                                                                      \
    if (DO_STAGE) {                                                            \
      stage4k(wt + (size_t)((t0 + (I) + 2) * 4 + nq) * 1024,                   \
              mybuf + (SLOT) * 1024, lane);                                    \
      SB(); /* keep stage4 before xl4 in issue order (vmcnt(4) split) */       \
      const float* xp = xt + (size_t)(t0 + (I) + 2) * R_TOTAL + r0;            \
      xn[SLOT][0] = *(const f32x4*)(xp + 0 + q * 4);                           \
      xn[SLOT][1] = *(const f32x4*)(xp + 16 + q * 4);                          \
      xn[SLOT][2] = *(const f32x4*)(xp + 32 + q * 4);                          \
      xn[SLOT][3] = *(const f32x4*)(xp + 48 + q * 4);                          \
    }                                                                          \
    SB();                                                                      \
    __builtin_amdgcn_s_setprio(1);                                             \
    _Pragma("unroll")                                                          \
    for (int f = 0; f < 4; ++f) {                                              \
      f32x4 Y = __builtin_amdgcn_mfma_f32_16x16x32_bf16(Ah[f].s, BCUR[0].s, zero4, 0, 0, 0); \
      Y = __builtin_amdgcn_mfma_f32_16x16x32_bf16(Ah[f].s, BCUR[1].s, Y, 0, 0, 0); \
      Y = __builtin_amdgcn_mfma_f32_16x16x32_bf16(Al[f].s, BCUR[0].s, Y, 0, 0, 0); \
      acc[f][0] += xlc[f] * Y;                                                 \
    }                                                                          \
    _Pragma("unroll")                                                          \
    for (int f = 0; f < 4; ++f) {                                              \
      f32x4 Y = __builtin_amdgcn_mfma_f32_16x16x32_bf16(Ah[f].s, BCUR[2].s, zero4, 0, 0, 0); \
      Y = __builtin_amdgcn_mfma_f32_16x16x32_bf16(Ah[f].s, BCUR[3].s, Y, 0, 0, 0); \
      Y = __builtin_amdgcn_mfma_f32_16x16x32_bf16(Al[f].s, BCUR[2].s, Y, 0, 0, 0); \
      acc[f][1] += xlc[f] * Y;                                                 \
    }                                                                          \
    __builtin_amdgcn_s_setprio(0);                                             \
    SB();                                                                      \
  }

// ---------------- main layer kernel ----------------
template <int NT, bool RELU, bool STORE_X>
__global__ __launch_bounds__(512, 2) void layer_mfma(
    const float* __restrict__ xt,    // NT x R (transposed prev activation)
    const float* __restrict__ x0t,   // 32 x R
    const u32* __restrict__ wt,      // NT*4 quarter images (1024 u32 each)
    const float* __restrict__ bias,  // 128
    float* __restrict__ xoutT,       // 128 x R (if STORE_X)
    float* __restrict__ osum)        // d_out + layer offset, stride 384
{
  constexpr int HT = NT / 2;
  static_assert((HT & 1) == 0 && HT >= 4, "pair-loop needs even HT >= 4");
  __shared__ u32 smem[16384];        // 64 KB: 8 waves x 2 KB-u32 (4 KB dbuf x2)

  const int tid = threadIdx.x;
  const int w = tid >> 6, lane = tid & 63;
  const int ln15 = lane & 15, q = lane >> 4;
  const int kh = w & 1, nq = w >> 1;
  const int r0 = blockIdx.x * 64;
  const int sw = ln15 & 7;
  u32* mybuf = smem + w * 2048;

  // ---- loop-invariant A fragments: split x0 rows (A[i=ln15][k=q*8+j]) ----
  PackU Ah[4], Al[4];
  #pragma unroll
  for (int f = 0; f < 4; ++f) {
    const int rbase = r0 + f * 16 + ln15;
    float e[8];
    #pragma unroll
    for (int j = 0; j < 8; ++j) e[j] = x0t[(size_t)(q * 8 + j) * R_TOTAL + rbase];
    #pragma unroll
    for (int jj = 0; jj < 4; ++jj) {
      float z0 = e[2 * jj], z1 = e[2 * jj + 1];
      Ah[f].u[jj] = pack_trunc(z0, z1);
      float h0 = __uint_as_float(__float_as_uint(z0) & 0xffff0000u);
      float h1 = __uint_as_float(__float_as_uint(z1) & 0xffff0000u);
      Al[f].u[jj] = pack_trunc(z0 - h0, z1 - h1);
    }
  }

  f32x4 acc[4][2];
  #pragma unroll
  for (int f = 0; f < 4; ++f)
    #pragma unroll
    for (int c = 0; c < 2; ++c) acc[f][c] = f32x4{0.f, 0.f, 0.f, 0.f};
  const f32x4 zero4 = {0.f, 0.f, 0.f, 0.f};

  const int t0 = kh * HT;

  // ---- prologue: issue G0 [stage|xl], G1 [stage|xl]; then expose slot 0 ----
  f32x4 xn[2][4];
  stage4k(wt + (size_t)(t0 * 4 + nq) * 1024, mybuf, lane);
  SB();
  {
    const float* xp = xt + (size_t)t0 * R_TOTAL + r0;
    xn[0][0] = *(const f32x4*)(xp + 0 + q * 4);
    xn[0][1] = *(const f32x4*)(xp + 16 + q * 4);
    xn[0][2] = *(const f32x4*)(xp + 32 + q * 4);
    xn[0][3] = *(const f32x4*)(xp + 48 + q * 4);
  }
  SB();
  stage4k(wt + (size_t)((t0 + 1) * 4 + nq) * 1024, mybuf + 1024, lane);
  SB();
  {
    const float* xp = xt + (size_t)(t0 + 1) * R_TOTAL + r0;
    xn[1][0] = *(const f32x4*)(xp + 0 + q * 4);
    xn[1][1] = *(const f32x4*)(xp + 16 + q * 4);
    xn[1][2] = *(const f32x4*)(xp + 32 + q * 4);
    xn[1][3] = *(const f32x4*)(xp + 48 + q * 4);
  }
  SB();
  // vmcnt(4): G0 fully done + G1 stages done (slot 0 readable; G1 xl in flight)
  __builtin_amdgcn_s_waitcnt(0x0F74);
  SB();
  PackB ba[4], bb[4];
  {
    const u32* nrow0 = mybuf + ln15 * 32;
    ba[0].v = *(const u32x4*)(nrow0 + ((q ^ sw) * 4));
    ba[1].v = *(const u32x4*)(nrow0 + (((4 + q) ^ sw) * 4));
    const u32* nrow1 = mybuf + (16 + ln15) * 32;
    ba[2].v = *(const u32x4*)(nrow1 + ((q ^ sw) * 4));
    ba[3].v = *(const u32x4*)(nrow1 + (((4 + q) ^ sw) * 4));
  }
  SB();

  // ---- steady state: iter i MFMAs from BCUR, reads slot i+1 into BNXT ----
  for (int i = 0; i < HT - 2; i += 2) {
    KITER(i,     0, 0x0F74, 0xC47F, 1, 1, ba, bb);
    KITER(i + 1, 1, 0x0F74, 0xC47F, 1, 1, bb, ba);
  }
  // ---- peeled last pair: no staging; final iter drains both counters ----
  KITER(HT - 2, 0, 0x0F74, 0xC47F, 0, 1, ba, bb);
  KITER(HT - 1, 1, 0x0F70, 0xC07F, 0, 0, bb, ba);

  // ---------------- epilogue ----------------
  __syncthreads();                  // K-loop LDS regions now reusable
  if (kh == 1) {                    // dump partial acc into own region (8 KB)
    u32* reg = mybuf;
    #pragma unroll
    for (int f = 0; f < 4; ++f)
      #pragma unroll
      for (int c = 0; c < 2; ++c)
        *(f32x4*)(reg + ((size_t)(f * 2 + c) * 64 + lane) * 4) = acc[f][c];
  }
  __syncthreads();
  if (kh == 0) {
    const u32* reg = smem + (w + 1) * 2048;   // partner (kh=1, same nq)
    float bs[2];
    #pragma unroll
    for (int c = 0; c < 2; ++c) bs[c] = bias[nq * 32 + c * 16 + ln15];

    f32x4 vv[4][2];
    #pragma unroll
    for (int f = 0; f < 4; ++f) {
      #pragma unroll
      for (int c = 0; c < 2; ++c) {
        f32x4 part = *(const f32x4*)(reg + ((size_t)(f * 2 + c) * 64 + lane) * 4);
        f32x4 v = acc[f][c] + part;
        v.x += bs[c]; v.y += bs[c]; v.z += bs[c]; v.w += bs[c];
        if (RELU) {
          v.x = fmaxf(v.x, 0.f); v.y = fmaxf(v.y, 0.f);
          v.z = fmaxf(v.z, 0.f); v.w = fmaxf(v.w, 0.f);
        }
        vv[f][c] = v;
        float s = v.x + v.y + v.z + v.w;       // 4 rows of batch (r0>>4)+f
        s += __shfl_xor(s, 16, 64);
        s += __shfl_xor(s, 32, 64);
        if (q == 0)
          osum[(size_t)((r0 >> 4) + f) * 384 + nq * 32 + c * 16 + ln15] = s;
      }
    }

    if (STORE_X) {
      // transpose via own LDS region, then 64B-contiguous stores to XT.
      u32* myreg = mybuf;
      #pragma unroll
      for (int f = 0; f < 4; ++f)
        #pragma unroll
        for (int c = 0; c < 2; ++c)
          *(f32x4*)(myreg + ((size_t)(f * 2 + c) * 64 + lane) * 4) = vv[f][c];
      // element (r_local, lcol): frag (f=r>>4, c=lcol>>4), lane q=(r>>2)&3,
      // ln15=lcol&15, comp rr=r&3. Round (c,s): lane -> col=c*16+(lane>>2),
      // r_local = s*16 + (lane&3)*4.
      #pragma unroll
      for (int c = 0; c < 2; ++c) {
        #pragma unroll
        for (int s = 0; s < 4; ++s) {
          f32x4 vr = *(const f32x4*)(myreg +
              ((size_t)(s * 2 + c) * 64 + (lane & 3) * 16 + (lane >> 2)) * 4);
          const int col = nq * 32 + c * 16 + (lane >> 2);
          *(f32x4*)&xoutT[(size_t)col * R_TOTAL + r0 + s * 16 + (lane & 3) * 4] = vr;
        }
      }
    }
  }
}

extern "C" void kernel_launch(void* const* d_in, const int* in_sizes, int n_in,
                              void* d_out, int out_size, void* d_ws, size_t ws_size,
                              hipStream_t stream) {
  const float* in = (const float*)d_in[0];
  const float* W0 = (const float*)d_in[1];
  const float* b0 = (const float*)d_in[2];
  const float* W1 = (const float*)d_in[3];
  const float* b1 = (const float*)d_in[4];
  const float* W2 = (const float*)d_in[5];
  const float* b2 = (const float*)d_in[6];
  float* out = (float*)d_out;

  float* X0T = (float*)d_ws;                         // 32 x 16384   (2 MB)
  float* X1T = X0T + (size_t)32 * R_TOTAL;           // 128 x 16384  (8 MB)
  float* X2T = X1T + (size_t)128 * R_TOTAL;          // 128 x 16384  (8 MB)
  u32* Wt0 = (u32*)(X2T + (size_t)128 * R_TOTAL);    // 32*4*1024 u32  (0.5 MB)
  u32* Wt1 = Wt0 + (size_t)32 * 4 * 1024;            // 128*4*1024 u32 (2 MB)
  u32* Wt2 = Wt1 + (size_t)128 * 4 * 1024;           // 128*4*1024 u32 (2 MB)
  // total ws: 22.5 MB

  prep_all<<<1280, 256, 0, stream>>>(in, X0T, W0, Wt0, W1, Wt1, W2, Wt2);

  layer_mfma<32, true, true><<<256, 512, 0, stream>>>(X0T, X0T, Wt0, b0, X1T, out + 0);
  layer_mfma<128, true, true><<<256, 512, 0, stream>>>(X1T, X0T, Wt1, b1, X2T, out + 128);
  layer_mfma<128, false, false><<<256, 512, 0, stream>>>(X2T, X0T, Wt2, b2, nullptr, out + 256);
}

// Round 6
// 181.975 us; speedup vs baseline: 2.0352x; 1.0354x over previous
//
#include <hip/hip_runtime.h>

// CIN_51539607712 — R8: shared-W blocks. Block = 256 rows x 32 cols (grid 256
// = 64 r-tiles x 4 col-quarters). 8 waves = (kh = w&1 K-half, rg = w>>1 row-
// group). Per-wave shape identical to R4 (64r x 32c, 24 MFMA/iter) but the 4
// rg-waves of each kh SHARE one 4 KB W image in LDS: each wave DMAs 1/4 of it
// (1 global_load_lds/iter/wave). Per-CU W staging: 32 KB -> 8 KB per iter
// (4x fewer TA/L1 requests — R4/R6/R7 showed the stall is a shared-throughput
// resource, not latency/occupancy). Cross-wave sync: 2 raw s_barriers per iter
// with counted vmcnt(5) (never 0 in-loop), uniform across waves.
// out[r,n] = sum_h xl[r,h] * Y_h[r,n],  Y_h[r,n] = sum_m x0[r,m] W[h*32+m,n].
// Y via 3 bf16 MFMAs (x0h*wh + x0h*wl + x0l*wh), then fp32 fma by xl (exact).
// vmem ledger: group(i) = [1 DMA-chunk, 4 xl] issued during iter i-2; top of
// iter i: vmcnt(5) leaves group(i+1) in flight, drains group(i). B1 after the
// vmcnt -> image i valid block-wide. lgkmcnt(0) + B2 -> all reads of slot done
// -> DMA(i+2) into same slot is WAR-safe. Final iter: vmcnt(0).
// History: R5 16-wave blocks -> VGPR64 spill (230MB). R6 32-row blocks ->
// MFMA/overhead ratio halved, regress. R7 reg-dbuf B-frags -> null.

typedef unsigned int u32;
typedef __attribute__((ext_vector_type(8))) short short8;
typedef __attribute__((ext_vector_type(4))) float f32x4;
typedef __attribute__((ext_vector_type(4))) u32 u32x4;

#define R_TOTAL 16384
#define GLOBAL_AS __attribute__((address_space(1)))
#define LDS_AS __attribute__((address_space(3)))

union PackU { u32 u[4]; short8 s; };
union PackB { u32x4 v; short8 s; };

// pack bf16(a) into low half, bf16(b) into high half (truncation)
__device__ __forceinline__ u32 pack_trunc(float a, float b) {
  return __builtin_amdgcn_perm(__float_as_uint(b), __float_as_uint(a), 0x07060302u);
}

// ---------------- fused prep kernel ----------------
// blocks 0..127: build X0T[m][b*16+d] = in[b][m][d]  (32 x 16384)
// blocks 128..255 / 256..767 / 768..1279: swizzle W0 / W1 / W2.
__device__ __forceinline__ void build_x0t_body(const float* __restrict__ in,
                                               float* __restrict__ x0t,
                                               int bid, int tid, float* t) {
  const int b0 = bid * 8;
  #pragma unroll
  for (int rep = 0; rep < 4; ++rep) {
    int idx = tid + rep * 256;
    *(float4*)&t[idx * 4] = *(const float4*)&in[(size_t)b0 * 512 + idx * 4];
  }
  __syncthreads();
  #pragma unroll
  for (int rep = 0; rep < 4; ++rep) {
    int idx = tid + rep * 256;     // 0..1023: m(32) x bl(8) x dq(4)
    int m = idx >> 5, rem = idx & 31;
    int bl = rem >> 2, dq = rem & 3;
    *(float4*)&x0t[(size_t)m * R_TOTAL + (b0 + bl) * 16 + dq * 4] =
        *(const float4*)&t[bl * 512 + m * 16 + dq * 4];
  }
}

// Block (t = bid>>2, nq = bid&3). Image: [nl 0..31][p 0..7] 16B blocks; position
// p holds logical block l = p ^ (nl&7); l = h*4+q -> split-part h of
// W[t*32+q*8+j][nq*32+nl], j pairs packed (even=lo half, odd=hi half).
__device__ __forceinline__ void swizzle_body(const float* __restrict__ W,
                                             u32* __restrict__ wt,
                                             int bid, int tid, float* wl) {
  const int t = bid >> 2, nq = bid & 3;
  {
    int kk = tid >> 3, c4 = tid & 7;
    float4 v = *(const float4*)&W[(size_t)(t * 32 + kk) * 128 + nq * 32 + c4 * 4];
    wl[kk * 33 + c4 * 4 + 0] = v.x;
    wl[kk * 33 + c4 * 4 + 1] = v.y;
    wl[kk * 33 + c4 * 4 + 2] = v.z;
    wl[kk * 33 + c4 * 4 + 3] = v.w;
  }
  __syncthreads();
  {
    int nl = tid >> 3, p = tid & 7;
    int l = p ^ (nl & 7);
    int h = l >> 2, q = l & 3;
    u32 o[4];
    #pragma unroll
    for (int jj = 0; jj < 4; ++jj) {
      float v0 = wl[(q * 8 + 2 * jj + 0) * 33 + nl];
      float v1 = wl[(q * 8 + 2 * jj + 1) * 33 + nl];
      if (h == 1) {
        v0 -= __uint_as_float(__float_as_uint(v0) & 0xffff0000u);
        v1 -= __uint_as_float(__float_as_uint(v1) & 0xffff0000u);
      }
      o[jj] = pack_trunc(v0, v1);
    }
    *(u32x4*)(wt + (size_t)(t * 4 + nq) * 1024 + nl * 32 + p * 4) =
        u32x4{o[0], o[1], o[2], o[3]};
  }
}

__global__ __launch_bounds__(256) void prep_all(
    const float* __restrict__ in, float* __restrict__ x0t,
    const float* __restrict__ W0, u32* __restrict__ wt0,
    const float* __restrict__ W1, u32* __restrict__ wt1,
    const float* __restrict__ W2, u32* __restrict__ wt2) {
  __shared__ float sh[4096];
  const int b = blockIdx.x, tid = threadIdx.x;
  if (b < 128)      build_x0t_body(in, x0t, b, tid, sh);
  else if (b < 256) swizzle_body(W0, wt0, b - 128, tid, sh);
  else if (b < 768) swizzle_body(W1, wt1, b - 256, tid, sh);
  else              swizzle_body(W2, wt2, b - 768, tid, sh);
}

// s_waitcnt imm (gfx9): vm[3:0]=b3:0, exp=b6:4, lgkm=b11:8, vm[5:4]=b15:14
// 0x0F75 = vmcnt(5)  0x0F70 = vmcnt(0)  0xC07F = lgkmcnt(0)
#define SB() __builtin_amdgcn_sched_barrier(0)

// KITER: one K-step (tile index t0+I, LDS slot SLOT = I&1).
#define KITER(I, SLOT, TOPW, DO_STAGE)                                         \
  {                                                                            \
    __builtin_amdgcn_s_waitcnt(TOPW);                                          \
    SB();                                                                      \
    __builtin_amdgcn_s_barrier(); /* B1: slot SLOT holds tile I block-wide */  \
    SB();                                                                      \
    PackB bh0, bl0, bh1, bl1;                                                  \
    {                                                                          \
      const u32* buf = kbuf + (SLOT) * 1024;                                   \
      const u32* row0 = buf + ln15 * 32;                                       \
      bh0.v = *(const u32x4*)(row0 + ((q ^ sw) * 4));                          \
      bl0.v = *(const u32x4*)(row0 + (((4 + q) ^ sw) * 4));                    \
      const u32* row1 = buf + (16 + ln15) * 32;                                \
      bh1.v = *(const u32x4*)(row1 + ((q ^ sw) * 4));                          \
      bl1.v = *(const u32x4*)(row1 + (((4 + q) ^ sw) * 4));                    \
    }                                                                          \
    f32x4 xlc[4];                                                              \
    xlc[0] = xn[SLOT][0]; xlc[1] = xn[SLOT][1];                                \
    xlc[2] = xn[SLOT][2]; xlc[3] = xn[SLOT][3];                                \
    __builtin_amdgcn_s_waitcnt(0xC07F); /* lgkmcnt(0): frags in regs */        \
    SB();                                                                      \
    __builtin_amdgcn_s_barrier(); /* B2: all reads of slot done (WAR-safe) */  \
    SB();                                                                      \
    if (DO_STAGE) {                                                            \
      const GLOBAL_AS u32* gp = (const GLOBAL_AS u32*)(                        \
          wt + (size_t)((t0 + (I) + 2) * 4 + nh) * 1024 + rg * 256);           \
      LDS_AS u32* lp = (LDS_AS u32*)(kbuf + (SLOT) * 1024 + rg * 256);         \
      __builtin_amdgcn_global_load_lds(gp + lane * 4, lp, 16, 0, 0);           \
      SB();                                                                    \
      const float* xp = xt + (size_t)(t0 + (I) + 2) * R_TOTAL + rbase0;        \
      xn[SLOT][0] = *(const f32x4*)(xp + 0 + q * 4);                           \
      xn[SLOT][1] = *(const f32x4*)(xp + 16 + q * 4);                          \
      xn[SLOT][2] = *(const f32x4*)(xp + 32 + q * 4);                          \
      xn[SLOT][3] = *(const f32x4*)(xp + 48 + q * 4);                          \
    }                                                                          \
    SB();                                                                      \
    __builtin_amdgcn_s_setprio(1);                                             \
    _Pragma("unroll")                                                          \
    for (int f = 0; f < 4; ++f) {                                              \
      f32x4 Y = __builtin_amdgcn_mfma_f32_16x16x32_bf16(Ah[f].s, bh0.s, zero4, 0, 0, 0); \
      Y = __builtin_amdgcn_mfma_f32_16x16x32_bf16(Ah[f].s, bl0.s, Y, 0, 0, 0); \
      Y = __builtin_amdgcn_mfma_f32_16x16x32_bf16(Al[f].s, bh0.s, Y, 0, 0, 0); \
      acc[f][0] += xlc[f] * Y;                                                 \
    }                                                                          \
    _Pragma("unroll")                                                          \
    for (int f = 0; f < 4; ++f) {                                              \
      f32x4 Y = __builtin_amdgcn_mfma_f32_16x16x32_bf16(Ah[f].s, bh1.s, zero4, 0, 0, 0); \
      Y = __builtin_amdgcn_mfma_f32_16x16x32_bf16(Ah[f].s, bl1.s, Y, 0, 0, 0); \
      Y = __builtin_amdgcn_mfma_f32_16x16x32_bf16(Al[f].s, bh1.s, Y, 0, 0, 0); \
      acc[f][1] += xlc[f] * Y;                                                 \
    }                                                                          \
    __builtin_amdgcn_s_setprio(0);                                             \
    SB();                                                                      \
  }

// ---------------- main layer kernel ----------------
// Block: 256 rows x 32 cols. 8 waves: kh = w&1 (K half), rg = w>>1 (64-row
// group). LDS 64 KB: [0..4096) u32 = 2 kh x 2 slots x 1024 shared W images;
// epilogue: kh=1 dumps at [8192 + rg*2048), kh=0 transpose at [rg*2048).
template <int NT, bool RELU, bool STORE_X>
__global__ __launch_bounds__(512, 2) void layer_mfma(
    const float* __restrict__ xt,    // NT x R (transposed prev activation)
    const float* __restrict__ x0t,   // 32 x R
    const u32* __restrict__ wt,      // NT*4 quarter images (1024 u32 each)
    const float* __restrict__ bias,  // 128
    float* __restrict__ xoutT,       // 128 x R (if STORE_X)
    float* __restrict__ osum)        // d_out + layer offset, stride 384
{
  constexpr int HT = NT / 2;
  static_assert((HT & 1) == 0 && HT >= 4, "pair-loop needs even HT >= 4");
  __shared__ u32 smem[16384];        // 64 KB

  const int tid = threadIdx.x;
  const int w = tid >> 6, lane = tid & 63;
  const int ln15 = lane & 15, q = lane >> 4;
  const int kh = w & 1, rg = w >> 1;
  const int r0 = (blockIdx.x >> 2) * 256;   // 64 r-tiles of 256 rows
  const int nh = blockIdx.x & 3;            // col quarter (32 cols)
  const int rbase0 = r0 + rg * 64;
  const int sw = ln15 & 7;
  u32* kbuf = smem + kh * 2048;             // shared image dbuf for this kh

  // ---- loop-invariant A fragments: split x0 rows (A[i=ln15][k=q*8+j]) ----
  PackU Ah[4], Al[4];
  #pragma unroll
  for (int f = 0; f < 4; ++f) {
    const int rbase = rbase0 + f * 16 + ln15;
    float e[8];
    #pragma unroll
    for (int j = 0; j < 8; ++j) e[j] = x0t[(size_t)(q * 8 + j) * R_TOTAL + rbase];
    #pragma unroll
    for (int jj = 0; jj < 4; ++jj) {
      float z0 = e[2 * jj], z1 = e[2 * jj + 1];
      Ah[f].u[jj] = pack_trunc(z0, z1);
      float h0 = __uint_as_float(__float_as_uint(z0) & 0xffff0000u);
      float h1 = __uint_as_float(__float_as_uint(z1) & 0xffff0000u);
      Al[f].u[jj] = pack_trunc(z0 - h0, z1 - h1);
    }
  }

  f32x4 acc[4][2];
  #pragma unroll
  for (int f = 0; f < 4; ++f)
    #pragma unroll
    for (int c = 0; c < 2; ++c) acc[f][c] = f32x4{0.f, 0.f, 0.f, 0.f};
  const f32x4 zero4 = {0.f, 0.f, 0.f, 0.f};

  const int t0 = kh * HT;

  // ---- prologue: per-wave groups [DMA-chunk, xl x4] for tiles 0 and 1 ----
  f32x4 xn[2][4];
  {
    const GLOBAL_AS u32* gp = (const GLOBAL_AS u32*)(
        wt + (size_t)(t0 * 4 + nh) * 1024 + rg * 256);
    LDS_AS u32* lp = (LDS_AS u32*)(kbuf + rg * 256);
    __builtin_amdgcn_global_load_lds(gp + lane * 4, lp, 16, 0, 0);
  }
  SB();
  {
    const float* xp = xt + (size_t)t0 * R_TOTAL + rbase0;
    xn[0][0] = *(const f32x4*)(xp + 0 + q * 4);
    xn[0][1] = *(const f32x4*)(xp + 16 + q * 4);
    xn[0][2] = *(const f32x4*)(xp + 32 + q * 4);
    xn[0][3] = *(const f32x4*)(xp + 48 + q * 4);
  }
  SB();
  {
    const GLOBAL_AS u32* gp = (const GLOBAL_AS u32*)(
        wt + (size_t)((t0 + 1) * 4 + nh) * 1024 + rg * 256);
    LDS_AS u32* lp = (LDS_AS u32*)(kbuf + 1024 + rg * 256);
    __builtin_amdgcn_global_load_lds(gp + lane * 4, lp, 16, 0, 0);
  }
  SB();
  {
    const float* xp = xt + (size_t)(t0 + 1) * R_TOTAL + rbase0;
    xn[1][0] = *(const f32x4*)(xp + 0 + q * 4);
    xn[1][1] = *(const f32x4*)(xp + 16 + q * 4);
    xn[1][2] = *(const f32x4*)(xp + 32 + q * 4);
    xn[1][3] = *(const f32x4*)(xp + 48 + q * 4);
  }
  SB();

  // ---- steady state: iter i stages chunk(i+2), waits vmcnt(5) ----
  for (int i = 0; i < HT - 2; i += 2) {
    KITER(i,     0, 0x0F75, 1);
    KITER(i + 1, 1, 0x0F75, 1);
  }
  // ---- peeled last pair: no staging; final iter drains vmcnt(0) ----
  KITER(HT - 2, 0, 0x0F75, 0);
  KITER(HT - 1, 1, 0x0F70, 0);

  // ---------------- epilogue ----------------
  __syncthreads();                  // K-loop LDS regions now reusable
  if (kh == 1) {                    // dump partial acc (8 KB per wave)
    u32* reg = smem + 8192 + rg * 2048;
    #pragma unroll
    for (int f = 0; f < 4; ++f)
      #pragma unroll
      for (int c = 0; c < 2; ++c)
        *(f32x4*)(reg + ((size_t)(f * 2 + c) * 64 + lane) * 4) = acc[f][c];
  }
  __syncthreads();
  if (kh == 0) {
    const u32* reg = smem + 8192 + rg * 2048;   // partner (kh=1, same rg)
    float bs[2];
    #pragma unroll
    for (int c = 0; c < 2; ++c) bs[c] = bias[nh * 32 + c * 16 + ln15];

    f32x4 vv[4][2];
    #pragma unroll
    for (int f = 0; f < 4; ++f) {
      #pragma unroll
      for (int c = 0; c < 2; ++c) {
        f32x4 part = *(const f32x4*)(reg + ((size_t)(f * 2 + c) * 64 + lane) * 4);
        f32x4 v = acc[f][c] + part;
        v.x += bs[c]; v.y += bs[c]; v.z += bs[c]; v.w += bs[c];
        if (RELU) {
          v.x = fmaxf(v.x, 0.f); v.y = fmaxf(v.y, 0.f);
          v.z = fmaxf(v.z, 0.f); v.w = fmaxf(v.w, 0.f);
        }
        vv[f][c] = v;
        float s = v.x + v.y + v.z + v.w;       // 4 rows of batch
        s += __shfl_xor(s, 16, 64);
        s += __shfl_xor(s, 32, 64);
        if (q == 0)
          osum[(size_t)((r0 >> 4) + rg * 4 + f) * 384 + nh * 32 + c * 16 + ln15] = s;
      }
    }

    if (STORE_X) {
      // transpose via own LDS region (dead staging area), 64B stores to XT.
      u32* myreg = smem + rg * 2048;
      #pragma unroll
      for (int f = 0; f < 4; ++f)
        #pragma unroll
        for (int c = 0; c < 2; ++c)
          *(f32x4*)(myreg + ((size_t)(f * 2 + c) * 64 + lane) * 4) = vv[f][c];
      #pragma unroll
      for (int c = 0; c < 2; ++c) {
        #pragma unroll
        for (int s = 0; s < 4; ++s) {
          f32x4 vr = *(const f32x4*)(myreg +
              ((size_t)(s * 2 + c) * 64 + (lane & 3) * 16 + (lane >> 2)) * 4);
          const int col = nh * 32 + c * 16 + (lane >> 2);
          *(f32x4*)&xoutT[(size_t)col * R_TOTAL + r0 + rg * 64 + s * 16 + (lane & 3) * 4] = vr;
        }
      }
    }
  }
}

extern "C" void kernel_launch(void* const* d_in, const int* in_sizes, int n_in,
                              void* d_out, int out_size, void* d_ws, size_t ws_size,
                              hipStream_t stream) {
  const float* in = (const float*)d_in[0];
  const float* W0 = (const float*)d_in[1];
  const float* b0 = (const float*)d_in[2];
  const float* W1 = (const float*)d_in[3];
  const float* b1 = (const float*)d_in[4];
  const float* W2 = (const float*)d_in[5];
  const float* b2 = (const float*)d_in[6];
  float* out = (float*)d_out;

  float* X0T = (float*)d_ws;                         // 32 x 16384   (2 MB)
  float* X1T = X0T + (size_t)32 * R_TOTAL;           // 128 x 16384  (8 MB)
  float* X2T = X1T + (size_t)128 * R_TOTAL;          // 128 x 16384  (8 MB)
  u32* Wt0 = (u32*)(X2T + (size_t)128 * R_TOTAL);    // 32*4*1024 u32  (0.5 MB)
  u32* Wt1 = Wt0 + (size_t)32 * 4 * 1024;            // 128*4*1024 u32 (2 MB)
  u32* Wt2 = Wt1 + (size_t)128 * 4 * 1024;           // 128*4*1024 u32 (2 MB)
  // total ws: 22.5 MB

  prep_all<<<1280, 256, 0, stream>>>(in, X0T, W0, Wt0, W1, Wt1, W2, Wt2);

  layer_mfma<32, true, true><<<256, 512, 0, stream>>>(X0T, X0T, Wt0, b0, X1T, out + 0);
  layer_mfma<128, true, true><<<256, 512, 0, stream>>>(X1T, X0T, Wt1, b1, X2T, out + 128);
  layer_mfma<128, false, false><<<256, 512, 0, stream>>>(X2T, X0T, Wt2, b2, nullptr, out + 256);
}